// Round 8
// baseline (283.411 us; speedup 1.0000x reference)
//
#include <hip/hip_runtime.h>
#include <math.h>

namespace {

constexpr int   kB     = 16;
constexpr int   kA     = 65536;
constexpr int   kM     = 32;
constexpr int   kC     = 20;
constexpr float kImg   = 600.0f;
constexpr int   kBlock = 256;
constexpr int   kGridX = kA / kBlock;           // 256

// d_ws layout: sA[512] float4 | sB[512] float4 | sC[512] float2 | acc[3]
constexpr size_t kOffB = (size_t)kB * kM;       // float4 units
constexpr size_t kOffC = 2 * kOffB;

__device__ __forceinline__ float smooth_l1(float d) {
    float ad = fabsf(d);
    return ad < 1.0f ? 0.5f * d * d : ad - 0.5f;
}

// Raw background focal term: sigmoid(x)^2 * softplus(x)   (alpha applied later)
__device__ __forceinline__ float bg_raw(float x) {
    float e  = __expf(-fabsf(x));                 // exp(-|x|)
    float u  = 1.0f + e;
    float r  = __builtin_amdgcn_rcpf(u);
    float lg = __logf(u);                         // log(1+e)
    float p  = (x >= 0.0f) ? r : e * r;           // sigmoid(x)
    float sp = lg + fmaxf(x, 0.0f);               // softplus(x)
    return p * p * sp;
}

// Target-class focal term: 0.25 * (1-sigmoid(x))^2 * softplus(-x)
__device__ __forceinline__ float tgt_contrib(float x) {
    float e  = __expf(-fabsf(x));
    float u  = 1.0f + e;
    float r  = __builtin_amdgcn_rcpf(u);
    float lg = __logf(u);
    float q  = (x >= 0.0f) ? e * r : r;           // 1 - sigmoid(x)
    float sp = lg + fmaxf(-x, 0.0f);              // softplus(-x)
    return 0.25f * q * q * sp;
}

// ---- Prep: targets -> per-image box tables (consumed via scalar loads) ----
__global__ __launch_bounds__(512) void prep_kernel(
    const float* __restrict__ targets,
    float4* __restrict__ sA,    // x1, y1, x2+1, y2+1
    float4* __restrict__ sB,    // cx, cy, w, h
    float2* __restrict__ sC)    // area, label
{
    const int i = threadIdx.x;           // 512 = kB*kM entries
    const float* t = targets + (size_t)i * 6;
    float cx = t[2] * kImg, cy = t[3] * kImg;
    float w  = t[4] * kImg, h  = t[5] * kImg;
    float x1  = cx - w * 0.5f,        y1  = cy - h * 0.5f;
    float x2p = cx + w * 0.5f + 1.0f, y2p = cy + h * 0.5f + 1.0f;
    sA[i] = make_float4(x1, y1, x2p, y2p);
    sB[i] = make_float4(cx, cy, w, h);
    sC[i] = make_float2((x2p - x1) * (y2p - y1), t[1]);
}

__global__ __launch_bounds__(kBlock) void retina_main(
    const float* __restrict__ loc_preds,   // [B, A, 4]
    const float* __restrict__ cls_preds,   // [B, A, C]
    const float* __restrict__ iou_boxes,   // [A, 4] xywh
    const float4* __restrict__ sA,         // [B*M]
    const float4* __restrict__ sB,         // [B*M]
    const float2* __restrict__ sC,         // [B*M]
    float* __restrict__ acc)               // [3] loc, cls, npos
{
    __shared__ float sredl[kBlock / 64];
    __shared__ float sredc[kBlock / 64];
    __shared__ int   sredn[kBlock / 64];

    const int b  = blockIdx.y;
    const int ab = blockIdx.x * kBlock;
    const int a  = ab + threadIdx.x;

    // ---- Issue ALL global vector loads up front; latency hides behind IoU ----
    const float4 an = *(const float4*)(iou_boxes + (size_t)a * 4);
    const float4 lp = *(const float4*)(loc_preds + ((size_t)b * kA + a) * 4);
    const float* cp0 = cls_preds + ((size_t)b * kA + ab) * kC;
    float4 cv[kC / 4];
#pragma unroll
    for (int i = 0; i < kC / 4; ++i)
        cv[i] = *(const float4*)(cp0 + ((size_t)i * kBlock + threadIdx.x) * 4);

    // Wave-uniform box tables -> SGPRs via constant cache.
    const float4* bA = sA + (size_t)b * kM;
    const float2* bC = sC + (size_t)b * kM;

    // ---- Phase 1: division-free IoU argmax ----
    const float ax1  = an.x - an.z * 0.5f;
    const float ay1  = an.y - an.w * 0.5f;
    const float ax2p = an.x + an.z * 0.5f + 1.0f;
    const float ay2p = an.y + an.w * 0.5f + 1.0f;
    const float aarea = (ax2p - ax1) * (ay2p - ay1);

    // Track best as a fraction (bi/bu); update iff inter*bu > bi*u.
    float bi = -1.0f, bu = 1.0f;
    int   mid = 0;
#pragma unroll
    for (int m = 0; m < kM; ++m) {
        const float4 q  = bA[m];
        const float  ta = bC[m].x;
        float w = fmaxf(fminf(ax2p, q.z) - fmaxf(ax1, q.x), 0.0f);
        float h = fmaxf(fminf(ay2p, q.w) - fmaxf(ay1, q.y), 0.0f);
        float inter = w * h;
        float u = aarea + ta - inter;
        bool upd = inter * bu > bi * u;    // strict > keeps first-max semantics
        bi  = upd ? inter : bi;
        bu  = upd ? u     : bu;
        mid = upd ? m     : mid;
    }

    const bool pos = 2.0f * bi >= bu;                        // iou >= 0.5
    const bool ign = (5.0f * bi > 2.0f * bu) && !pos;        // 0.4 < iou < 0.5

    float loc_sum = 0.0f;
    if (pos) {
        float4 mb = sB[(size_t)b * kM + mid];   // rare per-lane gather, L2-hot
        float ltx = (mb.x - an.x) * __builtin_amdgcn_rcpf(an.z);
        float lty = (mb.y - an.y) * __builtin_amdgcn_rcpf(an.w);
        float ltw = __logf(mb.z * __builtin_amdgcn_rcpf(an.z));
        float lth = __logf(mb.w * __builtin_amdgcn_rcpf(an.w));
        loc_sum = smooth_l1(lp.x - ltx) + smooth_l1(lp.y - lty) +
                  smooth_l1(lp.z - ltw) + smooth_l1(lp.w - lth);
    }

    // ---- Phase 2: dense focal sweep (raw, alpha folded out) ----
    float raw = 0.0f;
#pragma unroll
    for (int i = 0; i < kC / 4; ++i) {
        raw += bg_raw(cv[i].x) + bg_raw(cv[i].y) +
               bg_raw(cv[i].z) + bg_raw(cv[i].w);
    }

    // ---- Phase 3: sparse correction for this thread's own anchor ----
    float corr = 0.0f;
    if (pos | ign) {
        const float* own = cls_preds + ((size_t)b * kA + a) * kC;
        if (pos) {
            const int c = (int)bC[mid].y;      // label 0..19 (wave-divergent idx ok)
            float x = own[c];
            corr = tgt_contrib(x) - 0.75f * bg_raw(x);
        } else {
            float s = 0.0f;
#pragma unroll
            for (int i = 0; i < kC / 4; ++i) {
                float4 v = *(const float4*)(own + i * 4);
                s += bg_raw(v.x) + bg_raw(v.y) + bg_raw(v.z) + bg_raw(v.w);
            }
            corr = -0.75f * s;
        }
    }
    float cls_sum = 0.75f * raw + corr;

    // npos via ballot (no float shuffles needed)
    const unsigned long long pmask = __ballot(pos);
    const int lane = threadIdx.x & 63;
    const int wid  = threadIdx.x >> 6;

    // ---- Reduce loc & cls: wave shuffle -> LDS -> 3 atomics per block ----
#pragma unroll
    for (int off = 32; off > 0; off >>= 1) {
        loc_sum += __shfl_down(loc_sum, off);
        cls_sum += __shfl_down(cls_sum, off);
    }
    if (lane == 0) {
        sredl[wid] = loc_sum;
        sredc[wid] = cls_sum;
        sredn[wid] = (int)__popcll(pmask);
    }
    __syncthreads();
    if (threadIdx.x == 0) {
        float l = 0.0f, c = 0.0f;
        int   n = 0;
#pragma unroll
        for (int i = 0; i < kBlock / 64; ++i) {
            l += sredl[i]; c += sredc[i]; n += sredn[i];
        }
        atomicAdd(acc + 0, l);
        atomicAdd(acc + 1, c);
        atomicAdd(acc + 2, (float)n);
    }
}

__global__ void retina_final(const float* __restrict__ acc, float* __restrict__ out) {
    float loc = acc[0], cls = acc[1];
    float np  = fmaxf(1.0f, acc[2]);
    float inv = 1.0f / np;
    out[0] = (loc + cls) * inv;
    out[1] = loc * inv;
    out[2] = cls * inv;
}

}  // namespace

extern "C" void kernel_launch(void* const* d_in, const int* in_sizes, int n_in,
                              void* d_out, int out_size, void* d_ws, size_t ws_size,
                              hipStream_t stream) {
    const float* loc_preds = (const float*)d_in[0];
    const float* cls_preds = (const float*)d_in[1];
    const float* iou_boxes = (const float*)d_in[2];
    const float* targets   = (const float*)d_in[3];
    float* out = (float*)d_out;

    float4* sA = (float4*)d_ws;
    float4* sB = sA + kOffB;
    float2* sC = (float2*)(sA + kOffC);
    float*  acc = (float*)(sC + (size_t)kB * kM);

    hipMemsetAsync(acc, 0, 3 * sizeof(float), stream);
    prep_kernel<<<1, 512, 0, stream>>>(targets, sA, sB, sC);
    dim3 grid(kGridX, kB);
    retina_main<<<grid, kBlock, 0, stream>>>(loc_preds, cls_preds, iou_boxes,
                                             sA, sB, sC, acc);
    retina_final<<<1, 1, 0, stream>>>(acc, out);
}

// Round 9
// 159.458 us; speedup vs baseline: 1.7773x; 1.7773x over previous
//
#include <hip/hip_runtime.h>
#include <math.h>

namespace {

constexpr int   kB     = 16;
constexpr int   kA     = 65536;
constexpr int   kM     = 32;
constexpr int   kC     = 20;
constexpr float kImg   = 600.0f;
constexpr int   kBlock = 256;
constexpr int   kGridX = kA / kBlock;           // 256
constexpr int   kNBlocks = kGridX * kB;         // 4096

// d_ws layout: sA[512] float4 | sB[512] float4 | sC[512] float2 | partial[4096*3]
constexpr size_t kOffB = (size_t)kB * kM;       // float4 units
constexpr size_t kOffC = 2 * kOffB;

__device__ __forceinline__ float smooth_l1(float d) {
    float ad = fabsf(d);
    return ad < 1.0f ? 0.5f * d * d : ad - 0.5f;
}

// Raw background focal term: sigmoid(x)^2 * softplus(x)   (alpha applied later)
__device__ __forceinline__ float bg_raw(float x) {
    float e  = __expf(-fabsf(x));                 // exp(-|x|)
    float u  = 1.0f + e;
    float r  = __builtin_amdgcn_rcpf(u);
    float lg = __logf(u);                         // log(1+e)
    float p  = (x >= 0.0f) ? r : e * r;           // sigmoid(x)
    float sp = lg + fmaxf(x, 0.0f);               // softplus(x)
    return p * p * sp;
}

// Target-class focal term: 0.25 * (1-sigmoid(x))^2 * softplus(-x)
__device__ __forceinline__ float tgt_contrib(float x) {
    float e  = __expf(-fabsf(x));
    float u  = 1.0f + e;
    float r  = __builtin_amdgcn_rcpf(u);
    float lg = __logf(u);
    float q  = (x >= 0.0f) ? e * r : r;           // 1 - sigmoid(x)
    float sp = lg + fmaxf(-x, 0.0f);              // softplus(-x)
    return 0.25f * q * q * sp;
}

// ---- Prep: targets -> per-image box tables (consumed via scalar loads) ----
__global__ __launch_bounds__(512) void prep_kernel(
    const float* __restrict__ targets,
    float4* __restrict__ sA,    // x1, y1, x2+1, y2+1
    float4* __restrict__ sB,    // cx, cy, w, h
    float2* __restrict__ sC)    // area, label
{
    const int i = threadIdx.x;           // 512 = kB*kM entries
    const float* t = targets + (size_t)i * 6;
    float cx = t[2] * kImg, cy = t[3] * kImg;
    float w  = t[4] * kImg, h  = t[5] * kImg;
    float x1  = cx - w * 0.5f,        y1  = cy - h * 0.5f;
    float x2p = cx + w * 0.5f + 1.0f, y2p = cy + h * 0.5f + 1.0f;
    sA[i] = make_float4(x1, y1, x2p, y2p);
    sB[i] = make_float4(cx, cy, w, h);
    sC[i] = make_float2((x2p - x1) * (y2p - y1), t[1]);
}

__global__ __launch_bounds__(kBlock) void retina_main(
    const float* __restrict__ loc_preds,   // [B, A, 4]
    const float* __restrict__ cls_preds,   // [B, A, C]
    const float* __restrict__ iou_boxes,   // [A, 4] xywh
    const float4* __restrict__ sA,         // [B*M]
    const float4* __restrict__ sB,         // [B*M]
    const float2* __restrict__ sC,         // [B*M]
    float* __restrict__ partial)           // [kNBlocks][3]
{
    __shared__ float sredl[kBlock / 64];
    __shared__ float sredc[kBlock / 64];
    __shared__ int   sredn[kBlock / 64];

    const int b  = blockIdx.y;
    const int ab = blockIdx.x * kBlock;
    const int a  = ab + threadIdx.x;

    // ---- Issue ALL global vector loads up front; latency hides behind IoU ----
    const float4 an = *(const float4*)(iou_boxes + (size_t)a * 4);
    const float4 lp = *(const float4*)(loc_preds + ((size_t)b * kA + a) * 4);
    const float* cp0 = cls_preds + ((size_t)b * kA + ab) * kC;
    float4 cv[kC / 4];
#pragma unroll
    for (int i = 0; i < kC / 4; ++i)
        cv[i] = *(const float4*)(cp0 + ((size_t)i * kBlock + threadIdx.x) * 4);

    // Wave-uniform box tables -> SGPRs via constant cache.
    const float4* bA = sA + (size_t)b * kM;
    const float2* bC = sC + (size_t)b * kM;

    // ---- Phase 1: division-free IoU argmax ----
    const float ax1  = an.x - an.z * 0.5f;
    const float ay1  = an.y - an.w * 0.5f;
    const float ax2p = an.x + an.z * 0.5f + 1.0f;
    const float ay2p = an.y + an.w * 0.5f + 1.0f;
    const float aarea = (ax2p - ax1) * (ay2p - ay1);

    // Track best as a fraction (bi/bu); update iff inter*bu > bi*u.
    float bi = -1.0f, bu = 1.0f;
    int   mid = 0;
#pragma unroll
    for (int m = 0; m < kM; ++m) {
        const float4 q  = bA[m];
        const float  ta = bC[m].x;
        float w = fmaxf(fminf(ax2p, q.z) - fmaxf(ax1, q.x), 0.0f);
        float h = fmaxf(fminf(ay2p, q.w) - fmaxf(ay1, q.y), 0.0f);
        float inter = w * h;
        float u = aarea + ta - inter;
        bool upd = inter * bu > bi * u;    // strict > keeps first-max semantics
        bi  = upd ? inter : bi;
        bu  = upd ? u     : bu;
        mid = upd ? m     : mid;
    }

    const bool pos = 2.0f * bi >= bu;                        // iou >= 0.5
    const bool ign = (5.0f * bi > 2.0f * bu) && !pos;        // 0.4 < iou < 0.5

    float loc_sum = 0.0f;
    if (pos) {
        float4 mb = sB[(size_t)b * kM + mid];   // rare per-lane gather, L2-hot
        float ltx = (mb.x - an.x) * __builtin_amdgcn_rcpf(an.z);
        float lty = (mb.y - an.y) * __builtin_amdgcn_rcpf(an.w);
        float ltw = __logf(mb.z * __builtin_amdgcn_rcpf(an.z));
        float lth = __logf(mb.w * __builtin_amdgcn_rcpf(an.w));
        loc_sum = smooth_l1(lp.x - ltx) + smooth_l1(lp.y - lty) +
                  smooth_l1(lp.z - ltw) + smooth_l1(lp.w - lth);
    }

    // ---- Phase 2: dense focal sweep (raw, alpha folded out) ----
    float raw = 0.0f;
#pragma unroll
    for (int i = 0; i < kC / 4; ++i) {
        raw += bg_raw(cv[i].x) + bg_raw(cv[i].y) +
               bg_raw(cv[i].z) + bg_raw(cv[i].w);
    }

    // ---- Phase 3: sparse correction for this thread's own anchor ----
    float corr = 0.0f;
    if (pos | ign) {
        const float* own = cls_preds + ((size_t)b * kA + a) * kC;
        if (pos) {
            const int c = (int)bC[mid].y;      // label 0..19
            float x = own[c];
            corr = tgt_contrib(x) - 0.75f * bg_raw(x);
        } else {
            float s = 0.0f;
#pragma unroll
            for (int i = 0; i < kC / 4; ++i) {
                float4 v = *(const float4*)(own + i * 4);
                s += bg_raw(v.x) + bg_raw(v.y) + bg_raw(v.z) + bg_raw(v.w);
            }
            corr = -0.75f * s;
        }
    }
    float cls_sum = 0.75f * raw + corr;

    // npos via ballot (no float shuffles needed)
    const unsigned long long pmask = __ballot(pos);
    const int lane = threadIdx.x & 63;
    const int wid  = threadIdx.x >> 6;

    // ---- Reduce loc & cls: wave shuffle -> LDS -> per-block partial write ----
#pragma unroll
    for (int off = 32; off > 0; off >>= 1) {
        loc_sum += __shfl_down(loc_sum, off);
        cls_sum += __shfl_down(cls_sum, off);
    }
    if (lane == 0) {
        sredl[wid] = loc_sum;
        sredc[wid] = cls_sum;
        sredn[wid] = (int)__popcll(pmask);
    }
    __syncthreads();
    if (threadIdx.x == 0) {
        float l = 0.0f, c = 0.0f;
        int   n = 0;
#pragma unroll
        for (int i = 0; i < kBlock / 64; ++i) {
            l += sredl[i]; c += sredc[i]; n += sredn[i];
        }
        const int bid = blockIdx.y * gridDim.x + blockIdx.x;
        partial[3 * bid + 0] = l;
        partial[3 * bid + 1] = c;
        partial[3 * bid + 2] = (float)n;
    }
}

__global__ __launch_bounds__(1024) void retina_final(
    const float* __restrict__ partial, float* __restrict__ out)
{
    __shared__ float s[3][16];
    float l = 0.0f, c = 0.0f, n = 0.0f;
    for (int i = threadIdx.x; i < kNBlocks; i += 1024) {
        l += partial[3 * i + 0];
        c += partial[3 * i + 1];
        n += partial[3 * i + 2];
    }
#pragma unroll
    for (int off = 32; off > 0; off >>= 1) {
        l += __shfl_down(l, off);
        c += __shfl_down(c, off);
        n += __shfl_down(n, off);
    }
    const int lane = threadIdx.x & 63;
    const int wid  = threadIdx.x >> 6;
    if (lane == 0) { s[0][wid] = l; s[1][wid] = c; s[2][wid] = n; }
    __syncthreads();
    if (threadIdx.x == 0) {
        float L = 0.0f, C = 0.0f, N = 0.0f;
#pragma unroll
        for (int i = 0; i < 16; ++i) { L += s[0][i]; C += s[1][i]; N += s[2][i]; }
        float np  = fmaxf(1.0f, N);
        float inv = 1.0f / np;
        out[0] = (L + C) * inv;
        out[1] = L * inv;
        out[2] = C * inv;
    }
}

}  // namespace

extern "C" void kernel_launch(void* const* d_in, const int* in_sizes, int n_in,
                              void* d_out, int out_size, void* d_ws, size_t ws_size,
                              hipStream_t stream) {
    const float* loc_preds = (const float*)d_in[0];
    const float* cls_preds = (const float*)d_in[1];
    const float* iou_boxes = (const float*)d_in[2];
    const float* targets   = (const float*)d_in[3];
    float* out = (float*)d_out;

    float4* sA = (float4*)d_ws;
    float4* sB = sA + kOffB;
    float2* sC = (float2*)(sA + kOffC);
    float*  partial = (float*)(sC + (size_t)kB * kM);

    prep_kernel<<<1, 512, 0, stream>>>(targets, sA, sB, sC);
    dim3 grid(kGridX, kB);
    retina_main<<<grid, kBlock, 0, stream>>>(loc_preds, cls_preds, iou_boxes,
                                             sA, sB, sC, partial);
    retina_final<<<1, 1024, 0, stream>>>(partial, out);
}